// Round 1
// baseline (215.157 us; speedup 1.0000x reference)
//
#include <hip/hip_runtime.h>
#include <math.h>

#define BB 4
#define CI 64
#define CO 64
#define HH 96
#define WW 96
#define HW (HH*WW)
#define K2 9
#define PADC 1

// ws layout: mask [B][9][HW] floats, then wT [576][64] floats
#define MASK_FLOATS (BB*K2*HW)   // 331776 floats
#define WT_FLOATS   (576*64)     // 36864 floats

// ---------------- kernel 0: weight transpose wT[ck][o] = w[o][ck] ----------------
__global__ __launch_bounds__(256) void transpose_w(const float* __restrict__ wgt,
                                                   float* __restrict__ wT) {
    int i = blockIdx.x * 256 + threadIdx.x;   // over 576*64
    if (i < 576 * 64) {
        int ck = i >> 6, o = i & 63;
        wT[ck * 64 + o] = wgt[o * 576 + ck];
    }
}

// ---------------- kernel 1: mask conv + sigmoid ----------------
// grid 576 blocks (b,tile), block 256 = 64 px * 4 cgroups(16c each)
__global__ __launch_bounds__(256) void mask_kernel(const float* __restrict__ x,
                                                   const float* __restrict__ mw,
                                                   const float* __restrict__ mb,
                                                   float* __restrict__ mask) {
    __shared__ float red[4][K2][64];
    int t  = threadIdx.x;
    int px = t & 63;
    int cg = t >> 6;
    int bid = blockIdx.x;            // 576
    int b = bid / (HW / 64);         // /144
    int p = (bid % (HW / 64)) * 64 + px;
    int h = p / WW, w = p % WW;

    int nidx[9];
    #pragma unroll
    for (int i = 0; i < 3; i++)
        #pragma unroll
        for (int j = 0; j < 3; j++) {
            int hh = h + i - 1, ww = w + j - 1;
            bool v = (hh >= 0) && (hh < HH) && (ww >= 0) && (ww < WW);
            nidx[i * 3 + j] = v ? (hh * WW + ww) : -1;
        }

    float acc[K2];
    #pragma unroll
    for (int k = 0; k < K2; k++) acc[k] = 0.f;

    const float* xb = x + (size_t)b * CI * HW;
    for (int c = cg * 16; c < cg * 16 + 16; ++c) {
        float xv[9];
        #pragma unroll
        for (int q = 0; q < 9; q++)
            xv[q] = (nidx[q] >= 0) ? xb[c * HW + nidx[q]] : 0.f;
        #pragma unroll
        for (int k = 0; k < K2; k++) {
            const float* mwk = mw + ((size_t)k * CI + c) * 9;
            #pragma unroll
            for (int q = 0; q < 9; q++)
                acc[k] = fmaf(xv[q], mwk[q], acc[k]);
        }
    }
    #pragma unroll
    for (int k = 0; k < K2; k++) red[cg][k][px] = acc[k];
    __syncthreads();
    if (cg == 0) {
        #pragma unroll
        for (int k = 0; k < K2; k++) {
            float s = red[0][k][px] + red[1][k][px] + red[2][k][px] + red[3][k][px] + mb[k];
            mask[((size_t)b * K2 + k) * HW + p] = 1.f / (1.f + expf(-s));
        }
    }
}

// ---------------- kernel 2: fused deform sampling + GEMM ----------------
#define CC 8               // channels per chunk
#define NCHUNK (CI/CC)     // 8

__global__ __launch_bounds__(256) void deform_kernel(const float* __restrict__ x,
                                                     const float* __restrict__ off,
                                                     const float* __restrict__ wT,
                                                     const float* __restrict__ mask,
                                                     float* __restrict__ out) {
    __shared__ int   s_idx[K2][4][64];
    __shared__ float s_w[K2][4][64];
    __shared__ float s_val[CC * K2][64];

    int t  = threadIdx.x;
    int px = t & 63;
    int og = __builtin_amdgcn_readfirstlane(t >> 6);   // wave-uniform o-group
    int bid = blockIdx.x;                              // 576
    int b  = bid / (HW / 64);
    int p0 = (bid % (HW / 64)) * 64;

    // ---- phase 0: per (px,k) sampling metadata ----
    for (int e = t; e < K2 * 64; e += 256) {
        int k = e >> 6, pe = e & 63;
        int p = p0 + pe;
        int h = p / WW, w = p % WW;
        int ky = k / 3, kx = k % 3;
        float oy = off[((size_t)b * 2 * K2 + 2 * k) * HW + p];
        float ox = off[((size_t)b * 2 * K2 + 2 * k + 1) * HW + p];
        float m  = mask[((size_t)b * K2 + k) * HW + p];
        float py  = (float)(h - PADC + ky) + oy;
        float pxf = (float)(w - PADC + kx) + ox;
        float y0f = floorf(py), x0f = floorf(pxf);
        float wy = py - y0f, wx = pxf - x0f;
        int y0 = (int)y0f, x0 = (int)x0f;
        int y1 = y0 + 1, x1 = x0 + 1;
        int y0c = min(max(y0, 0), HH - 1), y1c = min(max(y1, 0), HH - 1);
        int x0c = min(max(x0, 0), WW - 1), x1c = min(max(x1, 0), WW - 1);
        bool vy0 = (y0 >= 0) && (y0 < HH), vy1 = (y1 >= 0) && (y1 < HH);
        bool vx0 = (x0 >= 0) && (x0 < WW), vx1 = (x1 >= 0) && (x1 < WW);
        float w00 = (1.f - wy) * (1.f - wx) * m; if (!(vy0 && vx0)) w00 = 0.f;
        float w01 = (1.f - wy) * wx * m;         if (!(vy0 && vx1)) w01 = 0.f;
        float w10 = wy * (1.f - wx) * m;         if (!(vy1 && vx0)) w10 = 0.f;
        float w11 = wy * wx * m;                 if (!(vy1 && vx1)) w11 = 0.f;
        s_idx[k][0][pe] = y0c * WW + x0c;
        s_idx[k][1][pe] = y0c * WW + x1c;
        s_idx[k][2][pe] = y1c * WW + x0c;
        s_idx[k][3][pe] = y1c * WW + x1c;
        s_w[k][0][pe] = w00; s_w[k][1][pe] = w01;
        s_w[k][2][pe] = w10; s_w[k][3][pe] = w11;
    }
    __syncthreads();

    float acc[16];
    #pragma unroll
    for (int i = 0; i < 16; i++) acc[i] = 0.f;

    const float* xb = x + (size_t)b * CI * HW;

    for (int ch = 0; ch < NCHUNK; ++ch) {
        // ---- phase 1: sample 8 channels x 9 taps for 64 pixels ----
        #pragma unroll
        for (int k = 0; k < K2; k++) {
            int   i0 = s_idx[k][0][px], i1 = s_idx[k][1][px];
            int   i2 = s_idx[k][2][px], i3 = s_idx[k][3][px];
            float w0 = s_w[k][0][px],  w1 = s_w[k][1][px];
            float w2 = s_w[k][2][px],  w3 = s_w[k][3][px];
            #pragma unroll
            for (int cl = 0; cl < 2; ++cl) {
                int c = ch * CC + og * 2 + cl;
                const float* xc = xb + c * HW;
                float v = xc[i0] * w0 + xc[i1] * w1 + xc[i2] * w2 + xc[i3] * w3;
                s_val[(og * 2 + cl) * K2 + k][px] = v;
            }
        }
        __syncthreads();

        // ---- phase 2: register GEMM, weights via wave-uniform scalar loads ----
        #pragma unroll 4
        for (int ckl = 0; ckl < CC * K2; ++ckl) {
            float s = s_val[ckl][px];
            const float* wp = wT + ((size_t)ch * CC * K2 + ckl) * 64 + (og << 4);
            #pragma unroll
            for (int oo = 0; oo < 16; oo++)
                acc[oo] = fmaf(s, wp[oo], acc[oo]);
        }
        __syncthreads();
    }

    // ---- epilogue ----
    #pragma unroll
    for (int oo = 0; oo < 16; oo++) {
        int o = (og << 4) + oo;
        out[((size_t)b * CO + o) * HW + p0 + px] = acc[oo];
    }
}

extern "C" void kernel_launch(void* const* d_in, const int* in_sizes, int n_in,
                              void* d_out, int out_size, void* d_ws, size_t ws_size,
                              hipStream_t stream) {
    const float* x   = (const float*)d_in[0];
    const float* off = (const float*)d_in[1];
    const float* wgt = (const float*)d_in[2];
    const float* mw  = (const float*)d_in[3];
    const float* mb  = (const float*)d_in[4];
    float* out = (float*)d_out;
    float* ws  = (float*)d_ws;
    float* maskp = ws;
    float* wT    = ws + MASK_FLOATS;

    hipLaunchKernelGGL(transpose_w, dim3(144), dim3(256), 0, stream, wgt, wT);
    hipLaunchKernelGGL(mask_kernel, dim3(576), dim3(256), 0, stream, x, mw, mb, maskp);
    hipLaunchKernelGGL(deform_kernel, dim3(576), dim3(256), 0, stream, x, off, wT, maskp, out);
}

// Round 2
// 121.988 us; speedup vs baseline: 1.7638x; 1.7638x over previous
//
#include <hip/hip_runtime.h>
#include <math.h>

#define BB 4
#define CI 64
#define CO 64
#define HH 96
#define WW 96
#define HW (HH*WW)      // 9216
#define K2 9
#define NT (HW/64)      // 144 tiles per batch
#define PADC 1

typedef __attribute__((ext_vector_type(8))) short short8;
typedef __attribute__((ext_vector_type(4))) float float4v;

// ws layout (bytes):
//   xT  : BB*HW*64 ushort = 4,718,592 B  (pixel-major bf16 x)
//   Wf  : 18*64*32 ushort = 73,728 B     (MFMA A-frag packed main weights)
//   MWf : 18*16*32 ushort = 18,432 B     (MFMA A-frag packed mask weights, rows 9..15 = 0)
#define XT_USHORTS ((size_t)BB*HW*64)
#define WF_USHORTS (18*64*32)
#define MWF_USHORTS (18*16*32)

__device__ __forceinline__ float bf2f(short s) {
    return __uint_as_float(((unsigned int)(unsigned short)s) << 16);
}
__device__ __forceinline__ short f2bf(float f) {
    unsigned int u = __float_as_uint(f);
    u = (u + 0x7fffu + ((u >> 16) & 1u)) >> 16;   // RNE
    return (short)u;
}

// ---------------- prep 1: x[b][c][hw] fp32 -> xT[b][p][c] bf16 (LDS transpose) ----
__global__ __launch_bounds__(256) void xt_kernel(const float* __restrict__ x,
                                                 unsigned short* __restrict__ xT) {
    __shared__ unsigned short tile[64][72];   // [px][c], padded
    int t = threadIdx.x, bid = blockIdx.x;
    int b = bid / NT, p0 = (bid % NT) * 64;
    int px = t & 63, cg = t >> 6;
    const float* xb = x + (size_t)b * CI * HW + p0;
    #pragma unroll
    for (int i = 0; i < 16; i++) {
        int c = cg * 16 + i;
        tile[px][c] = (unsigned short)f2bf(xb[(size_t)c * HW + px]);
    }
    __syncthreads();
    int c = t & 63, pg = t >> 6;
    unsigned short* xo = xT + ((size_t)b * HW + p0) * 64;
    #pragma unroll
    for (int i = 0; i < 16; i++) {
        int pp = pg * 16 + i;
        xo[(size_t)pp * 64 + c] = tile[pp][c];
    }
}

// ---------------- prep 2: pack Wf + MWf into A-frag order ----------------
// Wf[((k*2+cc)*64 + o)*32 + t] = bf16( w[o][c=cc*32+t][tap k] )
// MWf[((q*2+cc)*16 + m)*32 + t] = bf16( mw[m][c=cc*32+t][tap q] ), m<9 else 0
__global__ __launch_bounds__(256) void pack_kernel(const float* __restrict__ wgt,
                                                   const float* __restrict__ mw,
                                                   unsigned short* __restrict__ Wf,
                                                   unsigned short* __restrict__ MWf) {
    int i = blockIdx.x * 256 + threadIdx.x;
    if (i < WF_USHORTS) {
        int frag = i >> 11;           // /(64*32)
        int o = (i >> 5) & 63;
        int tt = i & 31;
        int k = frag >> 1, cc = frag & 1;
        int c = cc * 32 + tt;
        Wf[i] = (unsigned short)f2bf(wgt[o * 576 + c * 9 + k]);
    } else if (i < WF_USHORTS + MWF_USHORTS) {
        int e = i - WF_USHORTS;
        int frag = e >> 9;            // /(16*32)
        int m = (e >> 5) & 15;
        int tt = e & 31;
        int q = frag >> 1, cc = frag & 1;
        int c = cc * 32 + tt;
        MWf[e] = (m < 9) ? (unsigned short)f2bf(mw[m * 576 + c * 9 + q]) : 0;
    }
}

// ---------------- fused: mask conv (MFMA) + deform sample + GEMM (MFMA) -------
__global__ __launch_bounds__(256) void fused_kernel(const float* __restrict__ off,
                                                    const float* __restrict__ mbias,
                                                    const unsigned short* __restrict__ xT,
                                                    const unsigned short* __restrict__ Wf,
                                                    const unsigned short* __restrict__ MWf,
                                                    float* __restrict__ out) {
    __shared__ float s_mask[K2][64];
    __shared__ int   s_idx[K2][4][64];
    __shared__ float s_w[K2][4][64];

    int t = threadIdx.x;
    int lane = t & 63, wv = t >> 6;        // wave 0..3
    int n = lane & 15, quad = lane >> 4;
    int b = blockIdx.x / NT;
    int p0 = (blockIdx.x % NT) * 64;
    int pxl = wv * 16 + n;                 // pixel within tile for this lane
    int p = p0 + pxl;
    int h = p / WW, wc = p % WW;
    const unsigned short* xTb = xT + (size_t)b * HW * 64;

    // ---- phase A: mask conv via MFMA (rows 0..8 of a 16-row A) ----
    {
        float4v acc = {0.f, 0.f, 0.f, 0.f};
        #pragma unroll
        for (int q = 0; q < 9; q++) {
            int hh = h + q / 3 - 1, ww2 = wc + q % 3 - 1;
            bool valid = (hh >= 0) && (hh < HH) && (ww2 >= 0) && (ww2 < WW);
            int nidx = valid ? (hh * WW + ww2) : 0;
            const unsigned short* src = xTb + (size_t)nidx * 64 + quad * 8;
            #pragma unroll
            for (int cc = 0; cc < 2; cc++) {
                short8 bfrag = {0, 0, 0, 0, 0, 0, 0, 0};
                if (valid) bfrag = *(const short8*)(src + cc * 32);
                short8 afrag = *(const short8*)(MWf + ((size_t)((q * 2 + cc) * 16 + n)) * 32 + quad * 8);
                acc = __builtin_amdgcn_mfma_f32_16x16x32_bf16(afrag, bfrag, acc, 0, 0, 0);
            }
        }
        #pragma unroll
        for (int r = 0; r < 4; r++) {
            int row = quad * 4 + r;
            if (row < 9) {
                float s = acc[r] + mbias[row];
                s_mask[row][pxl] = 1.f / (1.f + expf(-s));
            }
        }
    }
    __syncthreads();

    // ---- phase B: sampling metadata (idx + mask-folded bilinear weights) ----
    for (int e = t; e < K2 * 64; e += 256) {
        int k = e >> 6, pe = e & 63;
        int pp = p0 + pe;
        int hh0 = pp / WW, ww0 = pp % WW;
        int ky = k / 3, kx = k % 3;
        float oy = off[((size_t)b * 2 * K2 + 2 * k) * HW + pp];
        float ox = off[((size_t)b * 2 * K2 + 2 * k + 1) * HW + pp];
        float m = s_mask[k][pe];
        float py = (float)(hh0 - PADC + ky) + oy;
        float pxf = (float)(ww0 - PADC + kx) + ox;
        float y0f = floorf(py), x0f = floorf(pxf);
        float wy = py - y0f, wx = pxf - x0f;
        int y0 = (int)y0f, x0 = (int)x0f;
        int y1 = y0 + 1, x1 = x0 + 1;
        int y0c = min(max(y0, 0), HH - 1), y1c = min(max(y1, 0), HH - 1);
        int x0c = min(max(x0, 0), WW - 1), x1c = min(max(x1, 0), WW - 1);
        bool vy0 = (y0 >= 0) && (y0 < HH), vy1 = (y1 >= 0) && (y1 < HH);
        bool vx0 = (x0 >= 0) && (x0 < WW), vx1 = (x1 >= 0) && (x1 < WW);
        float w00 = (1.f - wy) * (1.f - wx) * m; if (!(vy0 && vx0)) w00 = 0.f;
        float w01 = (1.f - wy) * wx * m;         if (!(vy0 && vx1)) w01 = 0.f;
        float w10 = wy * (1.f - wx) * m;         if (!(vy1 && vx0)) w10 = 0.f;
        float w11 = wy * wx * m;                 if (!(vy1 && vx1)) w11 = 0.f;
        s_idx[k][0][pe] = y0c * WW + x0c;
        s_idx[k][1][pe] = y0c * WW + x1c;
        s_idx[k][2][pe] = y1c * WW + x0c;
        s_idx[k][3][pe] = y1c * WW + x1c;
        s_w[k][0][pe] = w00; s_w[k][1][pe] = w01;
        s_w[k][2][pe] = w10; s_w[k][3][pe] = w11;
    }
    __syncthreads();

    // ---- phase C: sample (in-register B-frags) + MFMA GEMM ----
    float4v acc0 = {0.f, 0.f, 0.f, 0.f};
    float4v acc1 = {0.f, 0.f, 0.f, 0.f};
    float4v acc2 = {0.f, 0.f, 0.f, 0.f};
    float4v acc3 = {0.f, 0.f, 0.f, 0.f};

    for (int k = 0; k < 9; k++) {
        int i0 = s_idx[k][0][pxl], i1 = s_idx[k][1][pxl];
        int i2 = s_idx[k][2][pxl], i3 = s_idx[k][3][pxl];
        float w0 = s_w[k][0][pxl], w1 = s_w[k][1][pxl];
        float w2 = s_w[k][2][pxl], w3 = s_w[k][3][pxl];
        #pragma unroll
        for (int cc = 0; cc < 2; cc++) {
            int co = cc * 32 + quad * 8;
            short8 u0 = *(const short8*)(xTb + (size_t)i0 * 64 + co);
            short8 u1 = *(const short8*)(xTb + (size_t)i1 * 64 + co);
            short8 u2 = *(const short8*)(xTb + (size_t)i2 * 64 + co);
            short8 u3 = *(const short8*)(xTb + (size_t)i3 * 64 + co);
            short8 bfrag;
            #pragma unroll
            for (int j = 0; j < 8; j++) {
                float v = bf2f(u0[j]) * w0 + bf2f(u1[j]) * w1 +
                          bf2f(u2[j]) * w2 + bf2f(u3[j]) * w3;
                bfrag[j] = f2bf(v);
            }
            const unsigned short* wp = Wf + (size_t)((k * 2 + cc) * 64) * 32 + quad * 8;
            short8 a0 = *(const short8*)(wp + (0 * 16 + n) * 32);
            short8 a1 = *(const short8*)(wp + (1 * 16 + n) * 32);
            short8 a2 = *(const short8*)(wp + (2 * 16 + n) * 32);
            short8 a3 = *(const short8*)(wp + (3 * 16 + n) * 32);
            acc0 = __builtin_amdgcn_mfma_f32_16x16x32_bf16(a0, bfrag, acc0, 0, 0, 0);
            acc1 = __builtin_amdgcn_mfma_f32_16x16x32_bf16(a1, bfrag, acc1, 0, 0, 0);
            acc2 = __builtin_amdgcn_mfma_f32_16x16x32_bf16(a2, bfrag, acc2, 0, 0, 0);
            acc3 = __builtin_amdgcn_mfma_f32_16x16x32_bf16(a3, bfrag, acc3, 0, 0, 0);
        }
    }

    // ---- epilogue: D layout col=lane&15 (px), row=quad*4+reg (o within strip) ----
    float* ob = out + (size_t)b * CO * HW + p0 + pxl;
    #pragma unroll
    for (int r = 0; r < 4; r++) {
        ob[(size_t)(0 * 16 + quad * 4 + r) * HW] = acc0[r];
        ob[(size_t)(1 * 16 + quad * 4 + r) * HW] = acc1[r];
        ob[(size_t)(2 * 16 + quad * 4 + r) * HW] = acc2[r];
        ob[(size_t)(3 * 16 + quad * 4 + r) * HW] = acc3[r];
    }
}

extern "C" void kernel_launch(void* const* d_in, const int* in_sizes, int n_in,
                              void* d_out, int out_size, void* d_ws, size_t ws_size,
                              hipStream_t stream) {
    const float* x   = (const float*)d_in[0];
    const float* off = (const float*)d_in[1];
    const float* wgt = (const float*)d_in[2];
    const float* mw  = (const float*)d_in[3];
    const float* mb  = (const float*)d_in[4];
    float* out = (float*)d_out;

    unsigned short* xT  = (unsigned short*)d_ws;
    unsigned short* Wf  = xT + XT_USHORTS;
    unsigned short* MWf = Wf + WF_USHORTS;

    hipLaunchKernelGGL(xt_kernel, dim3(BB * NT), dim3(256), 0, stream, x, xT);
    hipLaunchKernelGGL(pack_kernel, dim3((WF_USHORTS + MWF_USHORTS + 255) / 256), dim3(256),
                       0, stream, wgt, mw, Wf, MWf);
    hipLaunchKernelGGL(fused_kernel, dim3(BB * NT), dim3(256), 0, stream,
                       off, mb, xT, Wf, MWf, out);
}